// Round 1
// baseline (230.917 us; speedup 1.0000x reference)
//
#include <hip/hip_runtime.h>
#include <math.h>

#define NPOS 4096   // H*W
#define NB   4      // batch

typedef _Float16 f16;
typedef f16 f16x8 __attribute__((ext_vector_type(8)));
typedef float f32x4 __attribute__((ext_vector_type(4)));

// ---------------------------------------------------------------------------
// Kernel 1: QKV projection (1x1 conv == channel GEMM), pos folded into K.
//   q[b][n][o] = sum_c Wq[o][c] x[b][c][n] + bq[o]              -> [b][n][c] f16
//   k[b][n][o] = sum_c Wk[o][c] x[b][c][n] + bk[o] + pos[o][n]  -> [b][n][c] f16
//   v[b][o][n] = sum_c Wv[o][c] x[b][c][n] + bv[o]              -> [b][c][n] f16
// grid 256 = B * (N/64); block 256. Each thread: fixed o = tid&63,
// 16 positions (wave-uniform n => broadcast x loads), W staged transposed in
// LDS with +1-pad (stride 65) so both staging writes and reads are
// conflict-free.
// ---------------------------------------------------------------------------
__global__ __launch_bounds__(256) void qkv_proj(
    const float* __restrict__ x,
    const float* __restrict__ Wq, const float* __restrict__ bq,
    const float* __restrict__ Wk, const float* __restrict__ bk,
    const float* __restrict__ Wv, const float* __restrict__ bv,
    const float* __restrict__ rel_h, const float* __restrict__ rel_w,
    f16* __restrict__ qh, f16* __restrict__ kh, f16* __restrict__ vh)
{
    __shared__ float Wt[3][64 * 65];
    const int tid = threadIdx.x;
    const int b   = blockIdx.x >> 6;
    const int n0  = (blockIdx.x & 63) << 6;

    for (int i = tid; i < 4096; i += 256) {
        int o = i >> 6, c = i & 63;          // coalesced global read W[o][c]
        Wt[0][c * 65 + o] = Wq[i];
        Wt[1][c * 65 + o] = Wk[i];
        Wt[2][c * 65 + o] = Wv[i];
    }
    __syncthreads();

    const int o  = tid & 63;
    const int ng = tid >> 6;                 // wave id -> 16-position group

    float accq[16], acck[16], accv[16];
    #pragma unroll
    for (int i = 0; i < 16; ++i) { accq[i] = 0.f; acck[i] = 0.f; accv[i] = 0.f; }

    const float* xrow = x + (size_t)(b * 64) * NPOS + n0 + ng * 16;
    for (int c = 0; c < 64; ++c) {
        float w0 = Wt[0][c * 65 + o];
        float w1 = Wt[1][c * 65 + o];
        float w2 = Wt[2][c * 65 + o];
        const float* xr = xrow + (size_t)c * NPOS;
        #pragma unroll
        for (int i = 0; i < 16; ++i) {
            float xv = xr[i];                // wave-uniform broadcast load
            accq[i] += w0 * xv;
            acck[i] += w1 * xv;
            accv[i] += w2 * xv;
        }
    }

    const float bqv = bq[o], bkv = bk[o], bvv = bv[o];
    #pragma unroll
    for (int i = 0; i < 16; ++i) {
        int n = n0 + ng * 16 + i;
        int h = n >> 6, w = n & 63;
        qh[((size_t)b * NPOS + n) * 64 + o] = (f16)(accq[i] + bqv);
        kh[((size_t)b * NPOS + n) * 64 + o] =
            (f16)(acck[i] + bkv + rel_h[o * 64 + h] + rel_w[o * 64 + w]);
        vh[((size_t)(b * 64 + o)) * NPOS + n] = (f16)(accv[i] + bvv);
    }
}

// ---------------------------------------------------------------------------
// Kernel 2: flash attention. grid 256 = B * (N/64); block 256 = 4 waves.
// Each wave owns a 16-row Q strip; block iterates 64-position K/V tiles.
// MFMA f32_16x16x32_f16; layouts per verified gfx950 mapping:
//   A-frag[j] = A[lane&15][quad*8+j],  B-frag[j] = B[quad*8+j][lane&15],
//   C/D:      row = quad*4+reg, col = lane&15.
// QK^T: A=Q row-major [n][c], B-frag = K row-major [m][c] (identical load).
// LDS tiles padded to stride 72 halves (144 B: 16B-aligned b128 reads, banks
// rotate by 4 words/row -> only free 2-way conflicts on B-frag reads).
// ---------------------------------------------------------------------------
#define LDP 72

__global__ __launch_bounds__(256) void attn(
    const f16* __restrict__ qh, const f16* __restrict__ kh,
    const f16* __restrict__ vh, float* __restrict__ out)
{
    __shared__ f16 Ks[64 * LDP];     // K-tile [m_local][c]
    __shared__ f16 Vt[64 * LDP];     // V-tile [c][m_local]
    __shared__ f16 Ps[4][16 * LDP];  // per-wave P strip [row][m_local]

    const int tid  = threadIdx.x;
    const int wave = tid >> 6;
    const int lane = tid & 63;
    const int quad = lane >> 4;
    const int l16  = lane & 15;
    const int b    = blockIdx.x >> 6;
    const int n0   = (blockIdx.x & 63) << 6;

    // Q A-fragments straight from global (row-major [n][c], 16B loads)
    const int qrow = n0 + wave * 16 + l16;
    const f16* qbase = qh + ((size_t)b * NPOS + qrow) * 64;
    const f16x8 aq0 = *(const f16x8*)(qbase + quad * 8);
    const f16x8 aq1 = *(const f16x8*)(qbase + 32 + quad * 8);

    f32x4 O[4] = {{0,0,0,0},{0,0,0,0},{0,0,0,0},{0,0,0,0}};
    float m_i[4], l_i[4];
    #pragma unroll
    for (int r = 0; r < 4; ++r) { m_i[r] = -1e30f; l_i[r] = 0.f; }

    // staging: 4 threads per row, 16 halves (2x16B) each
    const int srow = tid >> 2;
    const int sseg = (tid & 3) * 16;
    const f16* kb = kh + (size_t)b * NPOS * 64;
    const f16* vb = vh + (size_t)b * 64 * NPOS;

    for (int m0 = 0; m0 < NPOS; m0 += 64) {
        const f16* ksrc = kb + (size_t)(m0 + srow) * 64 + sseg;
        *(f16x8*)(&Ks[srow * LDP + sseg])     = *(const f16x8*)(ksrc);
        *(f16x8*)(&Ks[srow * LDP + sseg + 8]) = *(const f16x8*)(ksrc + 8);
        const f16* vsrc = vb + (size_t)srow * NPOS + m0 + sseg;
        *(f16x8*)(&Vt[srow * LDP + sseg])     = *(const f16x8*)(vsrc);
        *(f16x8*)(&Vt[srow * LDP + sseg + 8]) = *(const f16x8*)(vsrc + 8);
        __syncthreads();

        // S = Q K^T  (4 col-tiles of 16, K-dim 64 = 2 MFMAs)
        f32x4 S[4];
        #pragma unroll
        for (int t = 0; t < 4; ++t) {
            f32x4 acc = {0, 0, 0, 0};
            f16x8 b0 = *(const f16x8*)(&Ks[(t * 16 + l16) * LDP + quad * 8]);
            f16x8 b1 = *(const f16x8*)(&Ks[(t * 16 + l16) * LDP + 32 + quad * 8]);
            acc = __builtin_amdgcn_mfma_f32_16x16x32_f16(aq0, b0, acc, 0, 0, 0);
            acc = __builtin_amdgcn_mfma_f32_16x16x32_f16(aq1, b1, acc, 0, 0, 0);
            S[t] = acc;
        }

        // online softmax (row r lives on lanes sharing `quad`; 16-lane xor reduce)
        float p[4][4];
        float alpha[4];
        #pragma unroll
        for (int r = 0; r < 4; ++r) {
            float mx = fmaxf(fmaxf(S[0][r], S[1][r]), fmaxf(S[2][r], S[3][r]));
            #pragma unroll
            for (int d = 1; d <= 8; d <<= 1) mx = fmaxf(mx, __shfl_xor(mx, d));
            float mnew = fmaxf(m_i[r], mx);
            alpha[r] = __expf(m_i[r] - mnew);
            float rs = 0.f;
            #pragma unroll
            for (int t = 0; t < 4; ++t) {
                float e = __expf(S[t][r] - mnew);
                p[t][r] = e;
                rs += e;
            }
            #pragma unroll
            for (int d = 1; d <= 8; d <<= 1) rs += __shfl_xor(rs, d);
            m_i[r] = mnew;
            l_i[r] = l_i[r] * alpha[r] + rs;
        }

        // P (C-layout regs) -> LDS (row-major) for A-fragment reload; rescale O
        #pragma unroll
        for (int t = 0; t < 4; ++t) {
            #pragma unroll
            for (int r = 0; r < 4; ++r) {
                Ps[wave][(quad * 4 + r) * LDP + t * 16 + l16] = (f16)p[t][r];
                O[t][r] *= alpha[r];
            }
        }

        // O += P V   (A = P strip, B = V[m][c] read via transposed Vt[c][m])
        f16x8 ap0 = *(const f16x8*)(&Ps[wave][l16 * LDP + quad * 8]);
        f16x8 ap1 = *(const f16x8*)(&Ps[wave][l16 * LDP + 32 + quad * 8]);
        #pragma unroll
        for (int t = 0; t < 4; ++t) {
            f16x8 b0 = *(const f16x8*)(&Vt[(t * 16 + l16) * LDP + quad * 8]);
            f16x8 b1 = *(const f16x8*)(&Vt[(t * 16 + l16) * LDP + 32 + quad * 8]);
            O[t] = __builtin_amdgcn_mfma_f32_16x16x32_f16(ap0, b0, O[t], 0, 0, 0);
            O[t] = __builtin_amdgcn_mfma_f32_16x16x32_f16(ap1, b1, O[t], 0, 0, 0);
        }
        __syncthreads();   // protect Ks/Vt before next stage
    }

    // epilogue: out[b][c][n] = O[n][c] / l
    #pragma unroll
    for (int r = 0; r < 4; ++r) {
        float inv = 1.f / l_i[r];
        int n = n0 + wave * 16 + quad * 4 + r;
        #pragma unroll
        for (int t = 0; t < 4; ++t) {
            int c = t * 16 + l16;
            out[((size_t)(b * 64 + c)) * NPOS + n] = O[t][r] * inv;
        }
    }
}

// ---------------------------------------------------------------------------
extern "C" void kernel_launch(void* const* d_in, const int* in_sizes, int n_in,
                              void* d_out, int out_size, void* d_ws, size_t ws_size,
                              hipStream_t stream) {
    const float* x     = (const float*)d_in[0];
    const float* Wq    = (const float*)d_in[1];
    const float* bq    = (const float*)d_in[2];
    const float* Wk    = (const float*)d_in[3];
    const float* bk    = (const float*)d_in[4];
    const float* Wv    = (const float*)d_in[5];
    const float* bv    = (const float*)d_in[6];
    const float* rel_h = (const float*)d_in[7];
    const float* rel_w = (const float*)d_in[8];
    float* out = (float*)d_out;

    // workspace: q,k,v in f16 — 3 * 4*4096*64 * 2 B = 6 MB
    f16* qh = (f16*)d_ws;
    f16* kh = qh + (size_t)NB * NPOS * 64;
    f16* vh = kh + (size_t)NB * NPOS * 64;

    qkv_proj<<<NB * (NPOS / 64), 256, 0, stream>>>(x, Wq, bq, Wk, bk, Wv, bv,
                                                   rel_h, rel_w, qh, kh, vh);
    attn<<<NB * (NPOS / 64), 256, 0, stream>>>(qh, kh, vh, out);
}

// Round 2
// 143.753 us; speedup vs baseline: 1.6063x; 1.6063x over previous
//
#include <hip/hip_runtime.h>
#include <math.h>

#define NPOS 4096   // H*W
#define NB   4      // batch
#define NROW (NB * NPOS)
#define SPLIT 4
#define MCHUNK (NPOS / SPLIT)

typedef _Float16 f16;
typedef f16 f16x4 __attribute__((ext_vector_type(4)));
typedef f16 f16x8 __attribute__((ext_vector_type(8)));
typedef float f32x4 __attribute__((ext_vector_type(4)));

// ---------------------------------------------------------------------------
// Kernel 1: QKV projection as MFMA GEMM.
// Per block: 64 positions x 192 outputs (q|k|v concat), K-dim = 64 channels.
// A = x^T [n][c] (staged to LDS with transpose+f16 convert),
// B-frag trick: row-major W_all[o][c] in LDS -> contiguous b128 B-fragments.
// C-layout: row=quad*4+r (position), col=l16 (output channel within tile).
// V epilogue transposed through LDS (reusing Xs) for coalesced [c][n] stores.
// ---------------------------------------------------------------------------
#define LDW 72

__global__ __launch_bounds__(256) void qkv_proj(
    const float* __restrict__ x,
    const float* __restrict__ Wq, const float* __restrict__ bq,
    const float* __restrict__ Wk, const float* __restrict__ bk,
    const float* __restrict__ Wv, const float* __restrict__ bv,
    const float* __restrict__ rel_h, const float* __restrict__ rel_w,
    f16* __restrict__ qh, f16* __restrict__ kh, f16* __restrict__ vh)
{
    __shared__ f16 Xs[64 * LDW];    // [n_local][c]
    __shared__ f16 Ws[192 * LDW];   // [o_all][c], o_all = mat*64 + o

    const int tid = threadIdx.x;
    const int b   = blockIdx.x >> 6;
    const int n0  = (blockIdx.x & 63) << 6;

    // stage W (3 x 64 x 64 fp32, coalesced float4 reads, row-major f16 writes)
    #pragma unroll
    for (int k = 0; k < 12; ++k) {
        int idx   = tid + k * 256;            // [0, 3072) float4s
        int orow  = idx >> 4;                 // 0..191
        int cseg  = (idx & 15) << 2;          // 0..60 step 4
        int mat   = orow >> 6;
        int o     = orow & 63;
        const float* wsrc = (mat == 0) ? Wq : ((mat == 1) ? Wk : Wv);
        float4 v = *(const float4*)(wsrc + o * 64 + cseg);
        f16x4 h; h[0] = (f16)v.x; h[1] = (f16)v.y; h[2] = (f16)v.z; h[3] = (f16)v.w;
        *(f16x4*)(&Ws[orow * LDW + cseg]) = h;
    }
    // stage X transposed (coalesced float4 reads of x[c][n], scatter f16 writes)
    #pragma unroll
    for (int k = 0; k < 4; ++k) {
        int idx  = tid + k * 256;             // [0, 1024) float4s
        int c    = idx >> 4;
        int nseg = (idx & 15) << 2;
        float4 v = *(const float4*)(x + ((size_t)(b * 64 + c)) * NPOS + n0 + nseg);
        Xs[(nseg + 0) * LDW + c] = (f16)v.x;
        Xs[(nseg + 1) * LDW + c] = (f16)v.y;
        Xs[(nseg + 2) * LDW + c] = (f16)v.z;
        Xs[(nseg + 3) * LDW + c] = (f16)v.w;
    }
    __syncthreads();

    const int wave = tid >> 6;
    const int lane = tid & 63;
    const int quad = lane >> 4;
    const int l16  = lane & 15;

    const f16x8 a0 = *(const f16x8*)(&Xs[(wave * 16 + l16) * LDW + quad * 8]);
    const f16x8 a1 = *(const f16x8*)(&Xs[(wave * 16 + l16) * LDW + 32 + quad * 8]);

    f32x4 acc[12];
    #pragma unroll
    for (int t = 0; t < 12; ++t) {
        f32x4 c0 = {0, 0, 0, 0};
        f16x8 b0 = *(const f16x8*)(&Ws[(t * 16 + l16) * LDW + quad * 8]);
        f16x8 b1 = *(const f16x8*)(&Ws[(t * 16 + l16) * LDW + 32 + quad * 8]);
        c0 = __builtin_amdgcn_mfma_f32_16x16x32_f16(a0, b0, c0, 0, 0, 0);
        c0 = __builtin_amdgcn_mfma_f32_16x16x32_f16(a1, b1, c0, 0, 0, 0);
        acc[t] = c0;
    }

    // q, k epilogue (direct stores, [n][c] layout)
    #pragma unroll
    for (int r = 0; r < 4; ++r) {
        int n = n0 + wave * 16 + quad * 4 + r;
        int h = n >> 6, w = n & 63;
        #pragma unroll
        for (int t = 0; t < 4; ++t) {
            int o = t * 16 + l16;
            qh[((size_t)b * NPOS + n) * 64 + o] = (f16)(acc[t][r] + bq[o]);
        }
        #pragma unroll
        for (int t = 4; t < 8; ++t) {
            int o = (t - 4) * 16 + l16;
            kh[((size_t)b * NPOS + n) * 64 + o] =
                (f16)(acc[t][r] + bk[o] + rel_h[o * 64 + h] + rel_w[o * 64 + w]);
        }
    }

    // v epilogue: transpose via LDS (reuse Xs) then coalesced [c][n] stores
    __syncthreads();
    #pragma unroll
    for (int r = 0; r < 4; ++r) {
        int nl = wave * 16 + quad * 4 + r;
        #pragma unroll
        for (int t = 8; t < 12; ++t) {
            int o = (t - 8) * 16 + l16;
            Xs[o * LDW + nl] = (f16)(acc[t][r] + bv[o]);
        }
    }
    __syncthreads();
    {
        int o  = tid >> 2;
        int ns = (tid & 3) << 4;
        f16* dst = vh + ((size_t)(b * 64 + o)) * NPOS + n0 + ns;
        *(f16x8*)(dst)     = *(const f16x8*)(&Xs[o * LDW + ns]);
        *(f16x8*)(dst + 8) = *(const f16x8*)(&Xs[o * LDW + ns + 8]);
    }
}

// ---------------------------------------------------------------------------
// Kernel 2: flash attention, split-K over SPLIT chunks of the m-dimension.
// grid = B * (N/64) * SPLIT = 1024 blocks -> 4 blocks/CU -> 4 waves/SIMD.
// Each block: 64-row Q tile x 1024-position K/V chunk, partial (O/l, m, l)
// written to workspace; combine kernel merges the SPLIT partials.
// ---------------------------------------------------------------------------
#define LDP 72

__global__ __launch_bounds__(256) void attn(
    const f16* __restrict__ qh, const f16* __restrict__ kh,
    const f16* __restrict__ vh,
    f16* __restrict__ Op, float* __restrict__ Mp, float* __restrict__ Lp)
{
    __shared__ f16 Ks[64 * LDP];     // K-tile [m_local][c]
    __shared__ f16 Vt[64 * LDP];     // V-tile [c][m_local]
    __shared__ f16 Ps[4][16 * LDP];  // per-wave P strip [row][m_local]

    const int tid  = threadIdx.x;
    const int wave = tid >> 6;
    const int lane = tid & 63;
    const int quad = lane >> 4;
    const int l16  = lane & 15;
    const int s    = blockIdx.x & (SPLIT - 1);
    const int tile = blockIdx.x / SPLIT;
    const int b    = tile >> 6;
    const int n0   = (tile & 63) << 6;

    const int qrow = n0 + wave * 16 + l16;
    const f16* qbase = qh + ((size_t)b * NPOS + qrow) * 64;
    const f16x8 aq0 = *(const f16x8*)(qbase + quad * 8);
    const f16x8 aq1 = *(const f16x8*)(qbase + 32 + quad * 8);

    f32x4 O[4] = {{0,0,0,0},{0,0,0,0},{0,0,0,0},{0,0,0,0}};
    float m_i[4], l_i[4];
    #pragma unroll
    for (int r = 0; r < 4; ++r) { m_i[r] = -1e30f; l_i[r] = 0.f; }

    const int srow = tid >> 2;
    const int sseg = (tid & 3) * 16;
    const f16* kb = kh + (size_t)b * NPOS * 64;
    const f16* vb = vh + (size_t)b * 64 * NPOS;

    for (int m0 = s * MCHUNK; m0 < (s + 1) * MCHUNK; m0 += 64) {
        const f16* ksrc = kb + (size_t)(m0 + srow) * 64 + sseg;
        *(f16x8*)(&Ks[srow * LDP + sseg])     = *(const f16x8*)(ksrc);
        *(f16x8*)(&Ks[srow * LDP + sseg + 8]) = *(const f16x8*)(ksrc + 8);
        const f16* vsrc = vb + (size_t)srow * NPOS + m0 + sseg;
        *(f16x8*)(&Vt[srow * LDP + sseg])     = *(const f16x8*)(vsrc);
        *(f16x8*)(&Vt[srow * LDP + sseg + 8]) = *(const f16x8*)(vsrc + 8);
        __syncthreads();

        f32x4 S[4];
        #pragma unroll
        for (int t = 0; t < 4; ++t) {
            f32x4 acc = {0, 0, 0, 0};
            f16x8 b0 = *(const f16x8*)(&Ks[(t * 16 + l16) * LDP + quad * 8]);
            f16x8 b1 = *(const f16x8*)(&Ks[(t * 16 + l16) * LDP + 32 + quad * 8]);
            acc = __builtin_amdgcn_mfma_f32_16x16x32_f16(aq0, b0, acc, 0, 0, 0);
            acc = __builtin_amdgcn_mfma_f32_16x16x32_f16(aq1, b1, acc, 0, 0, 0);
            S[t] = acc;
        }

        float p[4][4];
        float alpha[4];
        #pragma unroll
        for (int r = 0; r < 4; ++r) {
            float mx = fmaxf(fmaxf(S[0][r], S[1][r]), fmaxf(S[2][r], S[3][r]));
            #pragma unroll
            for (int d = 1; d <= 8; d <<= 1) mx = fmaxf(mx, __shfl_xor(mx, d));
            float mnew = fmaxf(m_i[r], mx);
            alpha[r] = __expf(m_i[r] - mnew);
            float rs = 0.f;
            #pragma unroll
            for (int t = 0; t < 4; ++t) {
                float e = __expf(S[t][r] - mnew);
                p[t][r] = e;
                rs += e;
            }
            #pragma unroll
            for (int d = 1; d <= 8; d <<= 1) rs += __shfl_xor(rs, d);
            m_i[r] = mnew;
            l_i[r] = l_i[r] * alpha[r] + rs;
        }

        #pragma unroll
        for (int t = 0; t < 4; ++t) {
            #pragma unroll
            for (int r = 0; r < 4; ++r) {
                Ps[wave][(quad * 4 + r) * LDP + t * 16 + l16] = (f16)p[t][r];
                O[t][r] *= alpha[r];
            }
        }

        f16x8 ap0 = *(const f16x8*)(&Ps[wave][l16 * LDP + quad * 8]);
        f16x8 ap1 = *(const f16x8*)(&Ps[wave][l16 * LDP + 32 + quad * 8]);
        #pragma unroll
        for (int t = 0; t < 4; ++t) {
            f16x8 b0 = *(const f16x8*)(&Vt[(t * 16 + l16) * LDP + quad * 8]);
            f16x8 b1 = *(const f16x8*)(&Vt[(t * 16 + l16) * LDP + 32 + quad * 8]);
            O[t] = __builtin_amdgcn_mfma_f32_16x16x32_f16(ap0, b0, O[t], 0, 0, 0);
            O[t] = __builtin_amdgcn_mfma_f32_16x16x32_f16(ap1, b1, O[t], 0, 0, 0);
        }
        __syncthreads();
    }

    // partial epilogue: Ohat = O/l (f16), plus (m, l) per row
    #pragma unroll
    for (int r = 0; r < 4; ++r) {
        float inv = 1.f / l_i[r];
        int n = n0 + wave * 16 + quad * 4 + r;
        size_t row = (size_t)b * NPOS + n;
        #pragma unroll
        for (int t = 0; t < 4; ++t) {
            int c = t * 16 + l16;
            Op[((size_t)s * NROW + row) * 64 + c] = (f16)(O[t][r] * inv);
        }
        if (l16 == 0) {
            Mp[(size_t)s * NROW + row] = m_i[r];
            Lp[(size_t)s * NROW + row] = l_i[r];
        }
    }
}

// ---------------------------------------------------------------------------
// Kernel 3: combine SPLIT partials. grid 256 = B * (N/64), block 256.
// out[b][c][n] = sum_s (l_s e^{m_s-M} / L) * Ohat_s[row][c];  LDS transpose
// for coalesced [c][n] float4 stores.
// ---------------------------------------------------------------------------
__global__ __launch_bounds__(256) void combine(
    const f16* __restrict__ Op, const float* __restrict__ Mp,
    const float* __restrict__ Lp, float* __restrict__ out)
{
    __shared__ float Ot[64 * 68];   // [n_local][c] padded

    const int tid = threadIdx.x;
    const int b   = blockIdx.x >> 6;
    const int n0  = (blockIdx.x & 63) << 6;

    {
        int nl = tid >> 2;
        int cs = (tid & 3) << 4;
        size_t row = (size_t)b * NPOS + n0 + nl;

        float m[SPLIT], l[SPLIT];
        float M = -1e30f;
        #pragma unroll
        for (int s = 0; s < SPLIT; ++s) {
            m[s] = Mp[(size_t)s * NROW + row];
            l[s] = Lp[(size_t)s * NROW + row];
            M = fmaxf(M, m[s]);
        }
        float w[SPLIT], L = 0.f;
        #pragma unroll
        for (int s = 0; s < SPLIT; ++s) { w[s] = l[s] * __expf(m[s] - M); L += w[s]; }
        float invL = 1.f / L;

        float val[16];
        #pragma unroll
        for (int j = 0; j < 16; ++j) val[j] = 0.f;
        #pragma unroll
        for (int s = 0; s < SPLIT; ++s) {
            const f16* op = Op + ((size_t)s * NROW + row) * 64 + cs;
            f16x8 o0 = *(const f16x8*)(op);
            f16x8 o1 = *(const f16x8*)(op + 8);
            float ws_ = w[s] * invL;
            #pragma unroll
            for (int j = 0; j < 8; ++j) {
                val[j]     += ws_ * (float)o0[j];
                val[8 + j] += ws_ * (float)o1[j];
            }
        }
        #pragma unroll
        for (int k = 0; k < 4; ++k) {
            float4 v4 = { val[4*k], val[4*k+1], val[4*k+2], val[4*k+3] };
            *(float4*)(&Ot[nl * 68 + cs + 4 * k]) = v4;
        }
    }
    __syncthreads();
    {
        int c  = tid >> 2;
        int ns = (tid & 3) << 4;
        float* dst = out + ((size_t)(b * 64 + c)) * NPOS + n0 + ns;
        #pragma unroll
        for (int k = 0; k < 4; ++k) {
            float4 v4 = { Ot[(ns + 4*k + 0) * 68 + c], Ot[(ns + 4*k + 1) * 68 + c],
                          Ot[(ns + 4*k + 2) * 68 + c], Ot[(ns + 4*k + 3) * 68 + c] };
            *(float4*)(&dst[4 * k]) = v4;
        }
    }
}

// ---------------------------------------------------------------------------
extern "C" void kernel_launch(void* const* d_in, const int* in_sizes, int n_in,
                              void* d_out, int out_size, void* d_ws, size_t ws_size,
                              hipStream_t stream) {
    const float* x     = (const float*)d_in[0];
    const float* Wq    = (const float*)d_in[1];
    const float* bq    = (const float*)d_in[2];
    const float* Wk    = (const float*)d_in[3];
    const float* bk    = (const float*)d_in[4];
    const float* Wv    = (const float*)d_in[5];
    const float* bv    = (const float*)d_in[6];
    const float* rel_h = (const float*)d_in[7];
    const float* rel_w = (const float*)d_in[8];
    float* out = (float*)d_out;

    // workspace: qh/kh/vh f16 (6 MB) + Op f16 (8 MB) + Mp/Lp f32 (0.5 MB)
    f16* qh = (f16*)d_ws;
    f16* kh = qh + (size_t)NROW * 64;
    f16* vh = kh + (size_t)NROW * 64;
    f16* Op = vh + (size_t)NROW * 64;
    float* Mp = (float*)(Op + (size_t)SPLIT * NROW * 64);
    float* Lp = Mp + (size_t)SPLIT * NROW;

    qkv_proj<<<NB * (NPOS / 64), 256, 0, stream>>>(x, Wq, bq, Wk, bk, Wv, bv,
                                                   rel_h, rel_w, qh, kh, vh);
    attn<<<NB * (NPOS / 64) * SPLIT, 256, 0, stream>>>(qh, kh, vh, Op, Mp, Lp);
    combine<<<NB * (NPOS / 64), 256, 0, stream>>>(Op, Mp, Lp, out);
}

// Round 4
// 128.760 us; speedup vs baseline: 1.7934x; 1.1164x over previous
//
#include <hip/hip_runtime.h>
#include <math.h>

#define NPOS 4096   // H*W
#define NB   4      // batch
#define NROW (NB * NPOS)
#define LOG2E 1.44269504088896f

typedef _Float16 f16;
typedef f16 f16x4 __attribute__((ext_vector_type(4)));
typedef f16 f16x8 __attribute__((ext_vector_type(8)));
typedef float f32x4 __attribute__((ext_vector_type(4)));

// ---------------------------------------------------------------------------
// Kernel 1: QKV projection as MFMA GEMM (64 pos x 192 out per block).
// q is pre-scaled by log2(e) so attention softmax can use raw exp2.
// ---------------------------------------------------------------------------
#define LDW 72

__global__ __launch_bounds__(256) void qkv_proj(
    const float* __restrict__ x,
    const float* __restrict__ Wq, const float* __restrict__ bq,
    const float* __restrict__ Wk, const float* __restrict__ bk,
    const float* __restrict__ Wv, const float* __restrict__ bv,
    const float* __restrict__ rel_h, const float* __restrict__ rel_w,
    f16* __restrict__ qh, f16* __restrict__ kh, f16* __restrict__ vh)
{
    __shared__ f16 Xs[64 * LDW];    // [n_local][c]
    __shared__ f16 Ws[192 * LDW];   // [o_all][c]

    const int tid = threadIdx.x;
    const int b   = blockIdx.x >> 6;
    const int n0  = (blockIdx.x & 63) << 6;

    #pragma unroll
    for (int k = 0; k < 12; ++k) {
        int idx  = tid + k * 256;
        int orow = idx >> 4;
        int cseg = (idx & 15) << 2;
        int mat  = orow >> 6;
        int o    = orow & 63;
        const float* wsrc = (mat == 0) ? Wq : ((mat == 1) ? Wk : Wv);
        float4 v = *(const float4*)(wsrc + o * 64 + cseg);
        f16x4 h; h[0] = (f16)v.x; h[1] = (f16)v.y; h[2] = (f16)v.z; h[3] = (f16)v.w;
        *(f16x4*)(&Ws[orow * LDW + cseg]) = h;
    }
    #pragma unroll
    for (int k = 0; k < 4; ++k) {
        int idx  = tid + k * 256;
        int c    = idx >> 4;
        int nseg = (idx & 15) << 2;
        float4 v = *(const float4*)(x + ((size_t)(b * 64 + c)) * NPOS + n0 + nseg);
        Xs[(nseg + 0) * LDW + c] = (f16)v.x;
        Xs[(nseg + 1) * LDW + c] = (f16)v.y;
        Xs[(nseg + 2) * LDW + c] = (f16)v.z;
        Xs[(nseg + 3) * LDW + c] = (f16)v.w;
    }
    __syncthreads();

    const int wave = tid >> 6;
    const int lane = tid & 63;
    const int quad = lane >> 4;
    const int l16  = lane & 15;

    const f16x8 a0 = *(const f16x8*)(&Xs[(wave * 16 + l16) * LDW + quad * 8]);
    const f16x8 a1 = *(const f16x8*)(&Xs[(wave * 16 + l16) * LDW + 32 + quad * 8]);

    f32x4 acc[12];
    #pragma unroll
    for (int t = 0; t < 12; ++t) {
        f32x4 c0 = {0, 0, 0, 0};
        f16x8 b0 = *(const f16x8*)(&Ws[(t * 16 + l16) * LDW + quad * 8]);
        f16x8 b1 = *(const f16x8*)(&Ws[(t * 16 + l16) * LDW + 32 + quad * 8]);
        c0 = __builtin_amdgcn_mfma_f32_16x16x32_f16(a0, b0, c0, 0, 0, 0);
        c0 = __builtin_amdgcn_mfma_f32_16x16x32_f16(a1, b1, c0, 0, 0, 0);
        acc[t] = c0;
    }

    #pragma unroll
    for (int r = 0; r < 4; ++r) {
        int n = n0 + wave * 16 + quad * 4 + r;
        int h = n >> 6, w = n & 63;
        #pragma unroll
        for (int t = 0; t < 4; ++t) {
            int o = t * 16 + l16;
            qh[((size_t)b * NPOS + n) * 64 + o] = (f16)((acc[t][r] + bq[o]) * LOG2E);
        }
        #pragma unroll
        for (int t = 4; t < 8; ++t) {
            int o = (t - 4) * 16 + l16;
            kh[((size_t)b * NPOS + n) * 64 + o] =
                (f16)(acc[t][r] + bk[o] + rel_h[o * 64 + h] + rel_w[o * 64 + w]);
        }
    }

    __syncthreads();
    #pragma unroll
    for (int r = 0; r < 4; ++r) {
        int nl = wave * 16 + quad * 4 + r;
        #pragma unroll
        for (int t = 8; t < 12; ++t) {
            int o = (t - 8) * 16 + l16;
            Xs[o * LDW + nl] = (f16)(acc[t][r] + bv[o]);
        }
    }
    __syncthreads();
    {
        int o  = tid >> 2;
        int ns = (tid & 3) << 4;
        f16* dst = vh + ((size_t)(b * 64 + o)) * NPOS + n0 + ns;
        *(f16x8*)(dst)     = *(const f16x8*)(&Xs[o * LDW + ns]);
        *(f16x8*)(dst + 8) = *(const f16x8*)(&Xs[o * LDW + ns + 8]);
    }
}

// ---------------------------------------------------------------------------
// Kernel 2: flash attention via S^T = K Q^T.
//   S^T C-layout: row = m = quad*4+r, col = n = l16  ->  softmax over m is
//   in-lane (16 regs) + 2 cross-quad shuffles; P stays in registers and IS
//   the 16x16x16 A-fragment (A[l16][quad*4+j] = P[n=l16][m=t*16+quad*4+j]).
//   PV: O[n][c] += P[n][m] V[m][c]; B-frag b64 from Vt[c][m].
// LDS = K tile + V^T tile only (18432 B) -> 8 blocks/CU at split 8.
// ---------------------------------------------------------------------------
#define LDP 72

__global__ __launch_bounds__(256, 8) void attn(
    const f16* __restrict__ qh, const f16* __restrict__ kh,
    const f16* __restrict__ vh,
    f16* __restrict__ Op, float* __restrict__ Mp, float* __restrict__ Lp,
    int split, int mchunk)
{
    __shared__ f16 Ks[64 * LDP];     // K-tile [m_local][c]
    __shared__ f16 Vt[64 * LDP];     // V-tile [c][m_local]

    const int tid  = threadIdx.x;
    const int wave = tid >> 6;
    const int lane = tid & 63;
    const int quad = lane >> 4;
    const int l16  = lane & 15;
    const int s    = blockIdx.x % split;
    const int tile = blockIdx.x / split;
    const int b    = tile >> 6;
    const int n0   = (tile & 63) << 6;

    // Q as B-operand (k=channel): B[quad*8+j][l16] = Q[n=l16][c=quad*8+j]
    const f16* qbase = qh + ((size_t)b * NPOS + n0 + wave * 16 + l16) * 64;
    const f16x8 bq0 = *(const f16x8*)(qbase + quad * 8);
    const f16x8 bq1 = *(const f16x8*)(qbase + 32 + quad * 8);

    f32x4 O[4] = {{0,0,0,0},{0,0,0,0},{0,0,0,0},{0,0,0,0}};
    float m_i = -1e30f, l_i = 0.f;

    const int srow = tid >> 2;
    const int sseg = (tid & 3) * 16;
    const f16* kb = kh + (size_t)b * NPOS * 64;
    const f16* vb = vh + (size_t)b * 64 * NPOS;

    const int m_begin = s * mchunk;
    for (int m0 = m_begin; m0 < m_begin + mchunk; m0 += 64) {
        const f16* ksrc = kb + (size_t)(m0 + srow) * 64 + sseg;
        *(f16x8*)(&Ks[srow * LDP + sseg])     = *(const f16x8*)(ksrc);
        *(f16x8*)(&Ks[srow * LDP + sseg + 8]) = *(const f16x8*)(ksrc + 8);
        const f16* vsrc = vb + (size_t)srow * NPOS + m0 + sseg;
        *(f16x8*)(&Vt[srow * LDP + sseg])     = *(const f16x8*)(vsrc);
        *(f16x8*)(&Vt[srow * LDP + sseg + 8]) = *(const f16x8*)(vsrc + 8);
        __syncthreads();

        // S^T = K Q^T  (4 m-tiles of 16; K-dim 64 = 2 chained MFMAs)
        f32x4 S[4];
        #pragma unroll
        for (int t = 0; t < 4; ++t) {
            f32x4 acc = {0, 0, 0, 0};
            f16x8 ak0 = *(const f16x8*)(&Ks[(t * 16 + l16) * LDP + quad * 8]);
            f16x8 ak1 = *(const f16x8*)(&Ks[(t * 16 + l16) * LDP + 32 + quad * 8]);
            acc = __builtin_amdgcn_mfma_f32_16x16x32_f16(ak0, bq0, acc, 0, 0, 0);
            acc = __builtin_amdgcn_mfma_f32_16x16x32_f16(ak1, bq1, acc, 0, 0, 0);
            S[t] = acc;
        }

        // online softmax for column n = l16 (log2 domain; q pre-scaled)
        float mx = S[0][0];
        #pragma unroll
        for (int t = 0; t < 4; ++t)
            #pragma unroll
            for (int r = 0; r < 4; ++r) mx = fmaxf(mx, S[t][r]);
        mx = fmaxf(mx, __shfl_xor(mx, 16));
        mx = fmaxf(mx, __shfl_xor(mx, 32));
        float mnew  = fmaxf(m_i, mx);
        float alpha = __builtin_amdgcn_exp2f(m_i - mnew);
        float p[4][4];
        float rs = 0.f;
        #pragma unroll
        for (int t = 0; t < 4; ++t)
            #pragma unroll
            for (int r = 0; r < 4; ++r) {
                float e = __builtin_amdgcn_exp2f(S[t][r] - mnew);
                p[t][r] = e;
                rs += e;
            }
        rs += __shfl_xor(rs, 16);
        rs += __shfl_xor(rs, 32);
        m_i = mnew;
        l_i = l_i * alpha + rs;

        // broadcast alpha from column owner (l16 == quad*4+r) and rescale O
        #pragma unroll
        for (int r = 0; r < 4; ++r) {
            float av = __shfl(alpha, quad * 20 + r);   // lane quad*16 + quad*4 + r
            O[0][r] *= av; O[1][r] *= av; O[2][r] *= av; O[3][r] *= av;
        }

        // pack P into 16x16x16 A-fragments (register-only f32->f16 converts)
        f16x4 pa[4];
        #pragma unroll
        for (int t = 0; t < 4; ++t) {
            f16x4 a;
            a[0] = (f16)p[t][0]; a[1] = (f16)p[t][1];
            a[2] = (f16)p[t][2]; a[3] = (f16)p[t][3];
            pa[t] = a;
        }

        // O += P V  (4 c-tiles x 4 m-steps of 16x16x16)
        #pragma unroll
        for (int u = 0; u < 4; ++u) {
            #pragma unroll
            for (int t = 0; t < 4; ++t) {
                f16x4 bf = *(const f16x4*)(&Vt[(u * 16 + l16) * LDP + t * 16 + quad * 4]);
                O[u] = __builtin_amdgcn_mfma_f32_16x16x16f16(pa[t], bf, O[u], 0, 0, 0);
            }
        }
        __syncthreads();
    }

    // partial epilogue
    #pragma unroll
    for (int r = 0; r < 4; ++r) {
        float lr  = __shfl(l_i, quad * 20 + r);
        float inv = 1.f / lr;
        int n = n0 + wave * 16 + quad * 4 + r;
        size_t row = (size_t)b * NPOS + n;
        #pragma unroll
        for (int u = 0; u < 4; ++u)
            Op[((size_t)s * NROW + row) * 64 + u * 16 + l16] = (f16)(O[u][r] * inv);
    }
    if (lane < 16) {
        size_t row = (size_t)b * NPOS + n0 + wave * 16 + l16;
        Mp[(size_t)s * NROW + row] = m_i;
        Lp[(size_t)s * NROW + row] = l_i;
    }
}

// ---------------------------------------------------------------------------
// Kernel 3: combine split partials (log2-domain weights, two-pass, no arrays).
// ---------------------------------------------------------------------------
__global__ __launch_bounds__(256) void combine(
    const f16* __restrict__ Op, const float* __restrict__ Mp,
    const float* __restrict__ Lp, float* __restrict__ out, int split)
{
    __shared__ float Ot[64 * 68];

    const int tid = threadIdx.x;
    const int b   = blockIdx.x >> 6;
    const int n0  = (blockIdx.x & 63) << 6;

    {
        int nl = tid >> 2;
        int cs = (tid & 3) << 4;
        size_t row = (size_t)b * NPOS + n0 + nl;

        float M = -1e30f;
        for (int s2 = 0; s2 < split; ++s2)
            M = fmaxf(M, Mp[(size_t)s2 * NROW + row]);

        float L = 0.f;
        float val[16];
        #pragma unroll
        for (int j = 0; j < 16; ++j) val[j] = 0.f;
        for (int s2 = 0; s2 < split; ++s2) {
            float w = Lp[(size_t)s2 * NROW + row] *
                      __builtin_amdgcn_exp2f(Mp[(size_t)s2 * NROW + row] - M);
            L += w;
            const f16* op = Op + ((size_t)s2 * NROW + row) * 64 + cs;
            f16x8 o0 = *(const f16x8*)(op);
            f16x8 o1 = *(const f16x8*)(op + 8);
            #pragma unroll
            for (int j = 0; j < 8; ++j) {
                val[j]     += w * (float)o0[j];
                val[8 + j] += w * (float)o1[j];
            }
        }
        float invL = 1.f / L;
        #pragma unroll
        for (int k = 0; k < 4; ++k) {
            float4 v4 = { val[4*k] * invL, val[4*k+1] * invL,
                          val[4*k+2] * invL, val[4*k+3] * invL };
            *(float4*)(&Ot[nl * 68 + cs + 4 * k]) = v4;
        }
    }
    __syncthreads();
    {
        int c  = tid >> 2;
        int ns = (tid & 3) << 4;
        float* dst = out + ((size_t)(b * 64 + c)) * NPOS + n0 + ns;
        #pragma unroll
        for (int k = 0; k < 4; ++k) {
            float4 v4 = { Ot[(ns + 4*k + 0) * 68 + c], Ot[(ns + 4*k + 1) * 68 + c],
                          Ot[(ns + 4*k + 2) * 68 + c], Ot[(ns + 4*k + 3) * 68 + c] };
            *(float4*)(&dst[4 * k]) = v4;
        }
    }
}

// ---------------------------------------------------------------------------
extern "C" void kernel_launch(void* const* d_in, const int* in_sizes, int n_in,
                              void* d_out, int out_size, void* d_ws, size_t ws_size,
                              hipStream_t stream) {
    const float* x     = (const float*)d_in[0];
    const float* Wq    = (const float*)d_in[1];
    const float* bq    = (const float*)d_in[2];
    const float* Wk    = (const float*)d_in[3];
    const float* bk    = (const float*)d_in[4];
    const float* Wv    = (const float*)d_in[5];
    const float* bv    = (const float*)d_in[6];
    const float* rel_h = (const float*)d_in[7];
    const float* rel_w = (const float*)d_in[8];
    float* out = (float*)d_out;

    const size_t qkv_elems = (size_t)NROW * 64;   // per tensor
    int split = 8;
    {
        size_t need = 3 * qkv_elems * sizeof(f16)
                    + (size_t)split * NROW * 64 * sizeof(f16)
                    + 2 * (size_t)split * NROW * sizeof(float);
        if (ws_size < need) split = 4;            // deterministic wrt ws_size
    }
    const int mchunk = NPOS / split;

    f16* qh = (f16*)d_ws;
    f16* kh = qh + qkv_elems;
    f16* vh = kh + qkv_elems;
    f16* Op = vh + qkv_elems;
    float* Mp = (float*)(Op + (size_t)split * NROW * 64);
    float* Lp = Mp + (size_t)split * NROW;

    qkv_proj<<<NB * (NPOS / 64), 256, 0, stream>>>(x, Wq, bq, Wk, bk, Wv, bv,
                                                   rel_h, rel_w, qh, kh, vh);
    attn<<<NB * (NPOS / 64) * split, 256, 0, stream>>>(qh, kh, vh, Op, Mp, Lp,
                                                       split, mchunk);
    combine<<<NB * (NPOS / 64), 256, 0, stream>>>(Op, Mp, Lp, out, split);
}